// Round 1
// baseline (441.503 us; speedup 1.0000x reference)
//
#include <hip/hip_runtime.h>
#include <cstddef>
#include <cstdint>

#define T_TOK 2048
#define HD 1024
#define ID 1024
#define NE 16
#define TOPK 4
#define BM 128
#define BN 128
#define BK 32
#define MT_MAX 96
#define SLOT_CAP (MT_MAX * BM)

typedef float f32x4 __attribute__((ext_vector_type(4)));
typedef __bf16 bf16x8 __attribute__((ext_vector_type(8)));

// ---- workspace layout (bytes) ----
#define WS_CNT 0                         // int[16]
#define WS_FILL 64                       // int[16]
#define WS_OFF 128                       // int[17]
#define WS_TILE_E 256                    // int[MT_MAX]
#define WS_SEL 1024                      // int[8192]
#define WS_RW (WS_SEL + 8192 * 4)        // float[8192]
#define WS_SLOT_TOK (WS_RW + 8192 * 4)   // int[SLOT_CAP]
#define WS_SLOT_W (WS_SLOT_TOK + SLOT_CAP * 4)  // float[SLOT_CAP]
#define WS_H1 (WS_SLOT_W + SLOT_CAP * 4)        // __bf16[SLOT_CAP][ID]

__device__ __forceinline__ f32x4 mfma16(bf16x8 a, bf16x8 b, f32x4 c) {
  return __builtin_amdgcn_mfma_f32_16x16x32_bf16(a, b, c, 0, 0, 0);
}

__device__ __forceinline__ void st_bf16x4(__bf16* dst, float4 v) {
  __bf16 tmp[4] = {(__bf16)v.x, (__bf16)v.y, (__bf16)v.z, (__bf16)v.w};
  *(uint2*)dst = *(const uint2*)tmp;
}

// ---------------- router: logits, top-4, softmax ----------------
__global__ void router_kernel(const float* __restrict__ x,
                              const float* __restrict__ gw,
                              const float* __restrict__ bias,
                              int* __restrict__ sel, float* __restrict__ rw,
                              int* __restrict__ cnt) {
  int t = blockIdx.x;
  int lane = threadIdx.x;
  const float4* xr = (const float4*)(x + (size_t)t * HD);

  float4 xv[4];
#pragma unroll
  for (int i = 0; i < 4; ++i) xv[i] = xr[lane + 64 * i];

  float lg[NE];
#pragma unroll
  for (int e = 0; e < NE; ++e) {
    const float4* wr = (const float4*)(gw + (size_t)e * HD);
    float s = 0.f;
#pragma unroll
    for (int i = 0; i < 4; ++i) {
      float4 wv = wr[lane + 64 * i];
      s += xv[i].x * wv.x + xv[i].y * wv.y + xv[i].z * wv.z + xv[i].w * wv.w;
    }
#pragma unroll
    for (int d = 32; d >= 1; d >>= 1) s += __shfl_xor(s, d);
    lg[e] = s;
  }

  float b[NE];
#pragma unroll
  for (int e = 0; e < NE; ++e) b[e] = lg[e] + bias[e];

  int selk[TOPK];
  float raw[TOPK];
  unsigned used = 0;
#pragma unroll
  for (int k = 0; k < TOPK; ++k) {
    float best = -3.4e38f;
    int bi = 0;
#pragma unroll
    for (int e = 0; e < NE; ++e) {
      if (!((used >> e) & 1) && b[e] > best) { best = b[e]; bi = e; }
    }
    used |= (1u << bi);
    selk[k] = bi;
    raw[k] = lg[bi];
  }
  // softmax over raw (unbiased) logits
  float m = raw[0];
#pragma unroll
  for (int k = 1; k < TOPK; ++k) m = fmaxf(m, raw[k]);
  float s = 0.f;
  float w[TOPK];
#pragma unroll
  for (int k = 0; k < TOPK; ++k) { w[k] = __expf(raw[k] - m); s += w[k]; }
  float inv = 1.f / s;
#pragma unroll
  for (int k = 0; k < TOPK; ++k) w[k] *= inv;

  if (lane < TOPK) {
    sel[t * TOPK + lane] = selk[lane];
    rw[t * TOPK + lane] = w[lane];
  }
  if (lane == 0) {
#pragma unroll
    for (int k = 0; k < TOPK; ++k) atomicAdd(&cnt[selk[k]], 1);
  }
}

// ---------------- scan: aligned offsets + metadata ----------------
__global__ void scan_meta(const int* __restrict__ cnt, int* __restrict__ off_g,
                          int* __restrict__ tile_e, int* __restrict__ slot_tok,
                          float* __restrict__ slot_w) {
  __shared__ int s_off[NE + 1];
  int tid = threadIdx.x;
  if (tid == 0) {
    int o = 0;
    for (int e = 0; e < NE; ++e) {
      s_off[e] = o;
      o += (cnt[e] + BM - 1) & ~(BM - 1);
    }
    s_off[NE] = o;
    for (int i = 0; i <= NE; ++i) off_g[i] = s_off[i];
  }
  __syncthreads();
  int shared_base = s_off[NE];
  int total = shared_base + T_TOK;

  for (int tt = tid; tt < MT_MAX; tt += 256) {
    int base = tt * BM;
    int e = -1;
    if (base < shared_base) {
      for (int q = NE - 1; q >= 0; --q)
        if (base >= s_off[q]) { e = q; break; }
    } else if (base < total) {
      e = NE;  // shared expert
    }
    tile_e[tt] = e;
  }

  for (int s = tid; s < total; s += 256) {
    if (s >= shared_base) {
      slot_tok[s] = s - shared_base;
      slot_w[s] = 1.0f;
    } else {
      int e = 0;
      for (int q = NE - 1; q >= 0; --q)
        if (s >= s_off[q]) { e = q; break; }
      if (s >= s_off[e] + cnt[e]) {  // padding slot
        slot_tok[s] = -1;
        slot_w[s] = 0.f;
      }
      // real routed slots written by fill_slots (runs after on stream)
    }
  }
}

// ---------------- fill routed slots ----------------
__global__ void fill_slots(const int* __restrict__ sel, const float* __restrict__ rw,
                           const int* __restrict__ off_g, int* __restrict__ fillc,
                           int* __restrict__ slot_tok, float* __restrict__ slot_w) {
  int idx = blockIdx.x * 256 + threadIdx.x;
  if (idx >= T_TOK * TOPK) return;
  int t = idx >> 2;
  int e = sel[idx];
  int pos = atomicAdd(&fillc[e], 1);
  int s = off_g[e] + pos;
  slot_tok[s] = t;
  slot_w[s] = rw[idx];
}

// ---------------- pass 1: h1 = silu(x w1^T) * (x w3^T) ----------------
__global__ __launch_bounds__(256, 2) void pass1_gemm(
    const float* __restrict__ x, const int* __restrict__ slot_tok,
    const int* __restrict__ tile_e, const float* __restrict__ w1,
    const float* __restrict__ w3, const float* __restrict__ sw1,
    const float* __restrict__ sw3, __bf16* __restrict__ h1) {
  int mt = blockIdx.x;
  int e = tile_e[mt];
  if (e < 0) return;
  int n0 = blockIdx.y * BN;
  int m0 = mt * BM;

  const float* wg;
  const float* wu;
  if (e == NE) { wg = sw1; wu = sw3; }
  else { wg = w1 + (size_t)e * ID * HD; wu = w3 + (size_t)e * ID * HD; }

  __shared__ __bf16 As[BM][BK + 8];
  __shared__ __bf16 Bg[BN][BK + 8];
  __shared__ __bf16 Bu[BN][BK + 8];

  int tid = threadIdx.x;
  int lrow = tid >> 1;
  int lcol = (tid & 1) * 16;
  int tokenA = slot_tok[m0 + lrow];
  const float* aptr = x + (size_t)(tokenA < 0 ? 0 : tokenA) * HD + lcol;
  const float* gptr = wg + (size_t)(n0 + lrow) * HD + lcol;
  const float* uptr = wu + (size_t)(n0 + lrow) * HD + lcol;

  int wave = tid >> 6, lane = tid & 63;
  int wm = (wave >> 1) * 64, wn = (wave & 1) * 64;
  int l16 = lane & 15, kch = lane >> 4;

  f32x4 accg[4][4] = {};
  f32x4 accu[4][4] = {};

  for (int k0 = 0; k0 < HD; k0 += BK) {
    float4 av[4], gv[4], uv[4];
#pragma unroll
    for (int j = 0; j < 4; ++j) {
      av[j] = (tokenA >= 0) ? *(const float4*)(aptr + k0 + 4 * j)
                            : make_float4(0.f, 0.f, 0.f, 0.f);
      gv[j] = *(const float4*)(gptr + k0 + 4 * j);
      uv[j] = *(const float4*)(uptr + k0 + 4 * j);
    }
    __syncthreads();
#pragma unroll
    for (int j = 0; j < 4; ++j) {
      st_bf16x4(&As[lrow][lcol + 4 * j], av[j]);
      st_bf16x4(&Bg[lrow][lcol + 4 * j], gv[j]);
      st_bf16x4(&Bu[lrow][lcol + 4 * j], uv[j]);
    }
    __syncthreads();

    bf16x8 af[4], gf[4], uf[4];
#pragma unroll
    for (int i = 0; i < 4; ++i) {
      af[i] = *(const bf16x8*)(&As[wm + i * 16 + l16][kch * 8]);
      gf[i] = *(const bf16x8*)(&Bg[wn + i * 16 + l16][kch * 8]);
      uf[i] = *(const bf16x8*)(&Bu[wn + i * 16 + l16][kch * 8]);
    }
#pragma unroll
    for (int mi = 0; mi < 4; ++mi)
#pragma unroll
      for (int ni = 0; ni < 4; ++ni) {
        accg[mi][ni] = mfma16(af[mi], gf[ni], accg[mi][ni]);
        accu[mi][ni] = mfma16(af[mi], uf[ni], accu[mi][ni]);
      }
  }

  // epilogue: h1 = silu(g) * u, bf16 store
#pragma unroll
  for (int mi = 0; mi < 4; ++mi) {
#pragma unroll
    for (int ni = 0; ni < 4; ++ni) {
#pragma unroll
      for (int j = 0; j < 4; ++j) {
        int row = m0 + wm + mi * 16 + kch * 4 + j;
        int col = n0 + wn + ni * 16 + l16;
        float g = accg[mi][ni][j];
        float u = accu[mi][ni][j];
        float hv = (g / (1.f + __expf(-g))) * u;
        h1[(size_t)row * ID + col] = (__bf16)hv;
      }
    }
  }
}

// ---------------- pass 2: out += g * (h1 w2^T) ----------------
__global__ __launch_bounds__(256, 2) void pass2_gemm(
    const __bf16* __restrict__ h1, const int* __restrict__ slot_tok,
    const float* __restrict__ slot_w, const int* __restrict__ tile_e,
    const float* __restrict__ w2, const float* __restrict__ sw2,
    float* __restrict__ out) {
  int mt = blockIdx.x;
  int e = tile_e[mt];
  if (e < 0) return;
  int n0 = blockIdx.y * BN;
  int m0 = mt * BM;

  const float* wd = (e == NE) ? sw2 : (w2 + (size_t)e * HD * ID);

  __shared__ __bf16 As[BM][BK + 8];
  __shared__ __bf16 Bs[BN][BK + 8];

  int tid = threadIdx.x;
  int lrow = tid >> 1;
  int lcol = (tid & 1) * 16;
  const __bf16* aptr = h1 + (size_t)(m0 + lrow) * ID + lcol;
  const float* bptr = wd + (size_t)(n0 + lrow) * ID + lcol;

  int wave = tid >> 6, lane = tid & 63;
  int wm = (wave >> 1) * 64, wn = (wave & 1) * 64;
  int l16 = lane & 15, kch = lane >> 4;

  f32x4 acc[4][4] = {};

  for (int k0 = 0; k0 < ID; k0 += BK) {
    uint4 a0 = *(const uint4*)(aptr + k0);
    uint4 a1 = *(const uint4*)(aptr + k0 + 8);
    float4 bv[4];
#pragma unroll
    for (int j = 0; j < 4; ++j) bv[j] = *(const float4*)(bptr + k0 + 4 * j);
    __syncthreads();
    *(uint4*)(&As[lrow][lcol]) = a0;
    *(uint4*)(&As[lrow][lcol + 8]) = a1;
#pragma unroll
    for (int j = 0; j < 4; ++j) st_bf16x4(&Bs[lrow][lcol + 4 * j], bv[j]);
    __syncthreads();

    bf16x8 af[4], bf[4];
#pragma unroll
    for (int i = 0; i < 4; ++i) {
      af[i] = *(const bf16x8*)(&As[wm + i * 16 + l16][kch * 8]);
      bf[i] = *(const bf16x8*)(&Bs[wn + i * 16 + l16][kch * 8]);
    }
#pragma unroll
    for (int mi = 0; mi < 4; ++mi)
#pragma unroll
      for (int ni = 0; ni < 4; ++ni)
        acc[mi][ni] = mfma16(af[mi], bf[ni], acc[mi][ni]);
  }

#pragma unroll
  for (int mi = 0; mi < 4; ++mi) {
#pragma unroll
    for (int j = 0; j < 4; ++j) {
      int row = m0 + wm + mi * 16 + kch * 4 + j;
      int token = slot_tok[row];
      if (token < 0) continue;
      float wgt = slot_w[row];
#pragma unroll
      for (int ni = 0; ni < 4; ++ni) {
        int col = n0 + wn + ni * 16 + l16;
        atomicAdd(out + (size_t)token * HD + col, wgt * acc[mi][ni][j]);
      }
    }
  }
}

// ---------------- launcher ----------------
extern "C" void kernel_launch(void* const* d_in, const int* in_sizes, int n_in,
                              void* d_out, int out_size, void* d_ws, size_t ws_size,
                              hipStream_t stream) {
  const float* x = (const float*)d_in[0];
  const float* gate_w = (const float*)d_in[1];
  const float* ebias = (const float*)d_in[2];
  const float* w1 = (const float*)d_in[3];
  const float* w2 = (const float*)d_in[4];
  const float* w3 = (const float*)d_in[5];
  const float* sw1 = (const float*)d_in[6];
  const float* sw2 = (const float*)d_in[7];
  const float* sw3 = (const float*)d_in[8];
  float* out = (float*)d_out;

  char* ws = (char*)d_ws;
  int* cnt = (int*)(ws + WS_CNT);
  int* fillc = (int*)(ws + WS_FILL);
  int* off_g = (int*)(ws + WS_OFF);
  int* tile_e = (int*)(ws + WS_TILE_E);
  int* sel = (int*)(ws + WS_SEL);
  float* rw = (float*)(ws + WS_RW);
  int* slot_tok = (int*)(ws + WS_SLOT_TOK);
  float* slot_w = (float*)(ws + WS_SLOT_W);
  __bf16* h1 = (__bf16*)(ws + WS_H1);

  hipMemsetAsync(d_out, 0, (size_t)T_TOK * HD * sizeof(float), stream);
  hipMemsetAsync(ws, 0, 128, stream);  // cnt + fillc

  router_kernel<<<T_TOK, 64, 0, stream>>>(x, gate_w, ebias, sel, rw, cnt);
  scan_meta<<<1, 256, 0, stream>>>(cnt, off_g, tile_e, slot_tok, slot_w);
  fill_slots<<<(T_TOK * TOPK + 255) / 256, 256, 0, stream>>>(sel, rw, off_g, fillc,
                                                             slot_tok, slot_w);
  pass1_gemm<<<dim3(MT_MAX, ID / BN), 256, 0, stream>>>(x, slot_tok, tile_e, w1, w3,
                                                        sw1, sw3, h1);
  pass2_gemm<<<dim3(MT_MAX, HD / BN), 256, 0, stream>>>(h1, slot_tok, slot_w, tile_e,
                                                        w2, sw2, out);
}

// Round 2
// 346.491 us; speedup vs baseline: 1.2742x; 1.2742x over previous
//
#include <hip/hip_runtime.h>
#include <cstddef>
#include <cstdint>

#define T_TOK 2048
#define HD 1024
#define ID 1024
#define NE 16
#define TOPK 4
#define BM 128
#define BN 128
#define BK 32
#define MT_MAX 96
#define SLOT_CAP (MT_MAX * BM)

typedef float f32x4 __attribute__((ext_vector_type(4)));
typedef __bf16 bf16x8 __attribute__((ext_vector_type(8)));

// ---- workspace layout (bytes) ----
#define WS_CNT 0                          // int[16]
#define WS_FILL 64                        // int[16]
#define WS_OFF 128                        // int[17]
#define WS_TILE_E 256                     // int[MT_MAX]
#define WS_SEL 1024                       // int[8192]
#define WS_RW (WS_SEL + 8192 * 4)         // float[8192]
#define WS_SLOT_TOK (WS_RW + 8192 * 4)    // int[SLOT_CAP]
#define WS_SLOT_W (WS_SLOT_TOK + SLOT_CAP * 4)   // float[SLOT_CAP]
#define WS_H1 (WS_SLOT_W + SLOT_CAP * 4)         // __bf16[SLOT_CAP][ID]
#define WS_XB (WS_H1 + (size_t)SLOT_CAP * ID * 2)        // __bf16[T][H]
#define WS_W1B (WS_XB + (size_t)T_TOK * HD * 2)          // bf16 E*I*H
#define WS_W2B (WS_W1B + (size_t)NE * ID * HD * 2)
#define WS_W3B (WS_W2B + (size_t)NE * HD * ID * 2)
#define WS_SW1B (WS_W3B + (size_t)NE * ID * HD * 2)
#define WS_SW2B (WS_SW1B + (size_t)ID * HD * 2)
#define WS_SW3B (WS_SW2B + (size_t)HD * ID * 2)
#define WS_NEED (WS_SW3B + (size_t)ID * HD * 2)

__device__ __forceinline__ f32x4 mfma16(bf16x8 a, bf16x8 b, f32x4 c) {
  return __builtin_amdgcn_mfma_f32_16x16x32_bf16(a, b, c, 0, 0, 0);
}

__device__ __forceinline__ void st_bf16x4(__bf16* dst, float4 v) {
  __bf16 tmp[4] = {(__bf16)v.x, (__bf16)v.y, (__bf16)v.z, (__bf16)v.w};
  *(uint2*)dst = *(const uint2*)tmp;
}

// async global(16B/lane) -> LDS, linear dest (m97 pattern)
__device__ __forceinline__ void gload16(const __bf16* g, __bf16* l) {
  __builtin_amdgcn_global_load_lds(
      (const __attribute__((address_space(1))) uint32_t*)g,
      (__attribute__((address_space(3))) uint32_t*)l, 16, 0, 0);
}

// ---------------- fp32 -> bf16 convert (8 elem/thread) ----------------
__global__ void cvt_bf16(const float* __restrict__ in, __bf16* __restrict__ out,
                         int n8) {
  int i = blockIdx.x * 256 + threadIdx.x;
  if (i >= n8) return;
  const float4* p = (const float4*)in + 2 * (size_t)i;
  float4 a = p[0], b = p[1];
  bf16x8 o;
  o[0] = (__bf16)a.x; o[1] = (__bf16)a.y; o[2] = (__bf16)a.z; o[3] = (__bf16)a.w;
  o[4] = (__bf16)b.x; o[5] = (__bf16)b.y; o[6] = (__bf16)b.z; o[7] = (__bf16)b.w;
  *(bf16x8*)(out + 8 * (size_t)i) = o;
}

// ---------------- router: logits, top-4, softmax ----------------
__global__ void router_kernel(const float* __restrict__ x,
                              const float* __restrict__ gw,
                              const float* __restrict__ bias,
                              int* __restrict__ sel, float* __restrict__ rw,
                              int* __restrict__ cnt) {
  int t = blockIdx.x;
  int lane = threadIdx.x;
  const float4* xr = (const float4*)(x + (size_t)t * HD);

  float4 xv[4];
#pragma unroll
  for (int i = 0; i < 4; ++i) xv[i] = xr[lane + 64 * i];

  float lg[NE];
#pragma unroll
  for (int e = 0; e < NE; ++e) {
    const float4* wr = (const float4*)(gw + (size_t)e * HD);
    float s = 0.f;
#pragma unroll
    for (int i = 0; i < 4; ++i) {
      float4 wv = wr[lane + 64 * i];
      s += xv[i].x * wv.x + xv[i].y * wv.y + xv[i].z * wv.z + xv[i].w * wv.w;
    }
#pragma unroll
    for (int d = 32; d >= 1; d >>= 1) s += __shfl_xor(s, d);
    lg[e] = s;
  }

  float b[NE];
#pragma unroll
  for (int e = 0; e < NE; ++e) b[e] = lg[e] + bias[e];

  int selk[TOPK];
  float raw[TOPK];
  unsigned used = 0;
#pragma unroll
  for (int k = 0; k < TOPK; ++k) {
    float best = -3.4e38f;
    int bi = 0;
#pragma unroll
    for (int e = 0; e < NE; ++e) {
      if (!((used >> e) & 1) && b[e] > best) { best = b[e]; bi = e; }
    }
    used |= (1u << bi);
    selk[k] = bi;
    raw[k] = lg[bi];
  }
  float m = raw[0];
#pragma unroll
  for (int k = 1; k < TOPK; ++k) m = fmaxf(m, raw[k]);
  float s = 0.f;
  float w[TOPK];
#pragma unroll
  for (int k = 0; k < TOPK; ++k) { w[k] = __expf(raw[k] - m); s += w[k]; }
  float inv = 1.f / s;
#pragma unroll
  for (int k = 0; k < TOPK; ++k) w[k] *= inv;

  if (lane < TOPK) {
    sel[t * TOPK + lane] = selk[lane];
    rw[t * TOPK + lane] = w[lane];
  }
  if (lane == 0) {
#pragma unroll
    for (int k = 0; k < TOPK; ++k) atomicAdd(&cnt[selk[k]], 1);
  }
}

// ---------------- scan: aligned offsets + metadata ----------------
__global__ void scan_meta(const int* __restrict__ cnt, int* __restrict__ off_g,
                          int* __restrict__ tile_e, int* __restrict__ slot_tok,
                          float* __restrict__ slot_w) {
  __shared__ int s_off[NE + 1];
  int tid = threadIdx.x;
  if (tid == 0) {
    int o = 0;
    for (int e = 0; e < NE; ++e) {
      s_off[e] = o;
      o += (cnt[e] + BM - 1) & ~(BM - 1);
    }
    s_off[NE] = o;
    for (int i = 0; i <= NE; ++i) off_g[i] = s_off[i];
  }
  __syncthreads();
  int shared_base = s_off[NE];
  int total = shared_base + T_TOK;

  for (int tt = tid; tt < MT_MAX; tt += 256) {
    int base = tt * BM;
    int e = -1;
    if (base < shared_base) {
      for (int q = NE - 1; q >= 0; --q)
        if (base >= s_off[q]) { e = q; break; }
    } else if (base < total) {
      e = NE;  // shared expert
    }
    tile_e[tt] = e;
  }

  for (int s = tid; s < total; s += 256) {
    if (s >= shared_base) {
      slot_tok[s] = s - shared_base;
      slot_w[s] = 1.0f;
    } else {
      int e = 0;
      for (int q = NE - 1; q >= 0; --q)
        if (s >= s_off[q]) { e = q; break; }
      if (s >= s_off[e] + cnt[e]) {  // padding slot
        slot_tok[s] = -1;
        slot_w[s] = 0.f;
      }
    }
  }
}

// ---------------- fill routed slots ----------------
__global__ void fill_slots(const int* __restrict__ sel, const float* __restrict__ rw,
                           const int* __restrict__ off_g, int* __restrict__ fillc,
                           int* __restrict__ slot_tok, float* __restrict__ slot_w) {
  int idx = blockIdx.x * 256 + threadIdx.x;
  if (idx >= T_TOK * TOPK) return;
  int t = idx >> 2;
  int e = sel[idx];
  int pos = atomicAdd(&fillc[e], 1);
  int s = off_g[e] + pos;
  slot_tok[s] = t;
  slot_w[s] = rw[idx];
}

// ============= bf16 fast path (m97 structure: global_load_lds, BK=32) =======

// pass 1: h1 = silu(x w1^T) * (x w3^T)
__global__ __launch_bounds__(256, 2) void pass1_bf16(
    const __bf16* __restrict__ xb, const int* __restrict__ slot_tok,
    const int* __restrict__ tile_e, const __bf16* __restrict__ w1b,
    const __bf16* __restrict__ w3b, const __bf16* __restrict__ sw1b,
    const __bf16* __restrict__ sw3b, __bf16* __restrict__ h1) {
  int mt = blockIdx.y;
  int e = tile_e[mt];
  if (e < 0) return;
  int n0 = blockIdx.x * BN;  // x = n-tile -> XCD gets a fixed column stripe
  int m0 = mt * BM;

  const __bf16* wg = (e == NE) ? sw1b : w1b + (size_t)e * ID * HD;
  const __bf16* wu = (e == NE) ? sw3b : w3b + (size_t)e * ID * HD;

  __shared__ __align__(16) __bf16 As[BM * BK];
  __shared__ __align__(16) __bf16 Bg[BN * BK];
  __shared__ __align__(16) __bf16 Bu[BN * BK];

  int tid = threadIdx.x;
  // staging chunks: c0=tid, c1=tid+256; row=c>>2, 8-elem col chunk=(c&3)*8
  int r0 = tid >> 2, r1 = r0 + 64;
  int c8 = (tid & 3) * 8;
  int tok0 = slot_tok[m0 + r0]; if (tok0 < 0) tok0 = 0;
  int tok1 = slot_tok[m0 + r1]; if (tok1 < 0) tok1 = 0;
  const __bf16* gA0 = xb + (size_t)tok0 * HD + c8;
  const __bf16* gA1 = xb + (size_t)tok1 * HD + c8;
  const __bf16* gG0 = wg + (size_t)(n0 + r0) * HD + c8;
  const __bf16* gG1 = wg + (size_t)(n0 + r1) * HD + c8;
  const __bf16* gU0 = wu + (size_t)(n0 + r0) * HD + c8;
  const __bf16* gU1 = wu + (size_t)(n0 + r1) * HD + c8;
  __bf16* lA0 = &As[(size_t)tid * 8];
  __bf16* lA1 = &As[(size_t)(tid + 256) * 8];
  __bf16* lG0 = &Bg[(size_t)tid * 8];
  __bf16* lG1 = &Bg[(size_t)(tid + 256) * 8];
  __bf16* lU0 = &Bu[(size_t)tid * 8];
  __bf16* lU1 = &Bu[(size_t)(tid + 256) * 8];

  int wave = tid >> 6, lane = tid & 63;
  int wm = (wave >> 1) * 64, wn = (wave & 1) * 64;
  int l16 = lane & 15, kch = lane >> 4;

  f32x4 accg[4][4] = {};
  f32x4 accu[4][4] = {};

  for (int k0 = 0; k0 < HD; k0 += BK) {
    gload16(gA0 + k0, lA0);
    gload16(gA1 + k0, lA1);
    gload16(gG0 + k0, lG0);
    gload16(gG1 + k0, lG1);
    gload16(gU0 + k0, lU0);
    gload16(gU1 + k0, lU1);
    __syncthreads();  // drains vmcnt -> LDS tile ready

    bf16x8 af[4], gf[4], uf[4];
#pragma unroll
    for (int i = 0; i < 4; ++i) {
      af[i] = *(const bf16x8*)(&As[(wm + i * 16 + l16) * BK + kch * 8]);
      gf[i] = *(const bf16x8*)(&Bg[(wn + i * 16 + l16) * BK + kch * 8]);
      uf[i] = *(const bf16x8*)(&Bu[(wn + i * 16 + l16) * BK + kch * 8]);
    }
#pragma unroll
    for (int mi = 0; mi < 4; ++mi)
#pragma unroll
      for (int ni = 0; ni < 4; ++ni) {
        accg[mi][ni] = mfma16(af[mi], gf[ni], accg[mi][ni]);
        accu[mi][ni] = mfma16(af[mi], uf[ni], accu[mi][ni]);
      }
    __syncthreads();  // all reads done before next-tile overwrite
  }

#pragma unroll
  for (int mi = 0; mi < 4; ++mi) {
#pragma unroll
    for (int ni = 0; ni < 4; ++ni) {
#pragma unroll
      for (int j = 0; j < 4; ++j) {
        int row = m0 + wm + mi * 16 + kch * 4 + j;
        int col = n0 + wn + ni * 16 + l16;
        float g = accg[mi][ni][j];
        float u = accu[mi][ni][j];
        float hv = (g / (1.f + __expf(-g))) * u;
        h1[(size_t)row * ID + col] = (__bf16)hv;
      }
    }
  }
}

// pass 2: out += g * (h1 w2^T)
__global__ __launch_bounds__(256, 2) void pass2_bf16(
    const __bf16* __restrict__ h1, const int* __restrict__ slot_tok,
    const float* __restrict__ slot_w, const int* __restrict__ tile_e,
    const __bf16* __restrict__ w2b, const __bf16* __restrict__ sw2b,
    float* __restrict__ out) {
  int mt = blockIdx.y;
  int e = tile_e[mt];
  if (e < 0) return;
  int n0 = blockIdx.x * BN;
  int m0 = mt * BM;

  const __bf16* wd = (e == NE) ? sw2b : w2b + (size_t)e * HD * ID;

  __shared__ __align__(16) __bf16 As[BM * BK];
  __shared__ __align__(16) __bf16 Bs[BN * BK];

  int tid = threadIdx.x;
  int r0 = tid >> 2, r1 = r0 + 64;
  int c8 = (tid & 3) * 8;
  const __bf16* gA0 = h1 + (size_t)(m0 + r0) * ID + c8;
  const __bf16* gA1 = h1 + (size_t)(m0 + r1) * ID + c8;
  const __bf16* gB0 = wd + (size_t)(n0 + r0) * ID + c8;
  const __bf16* gB1 = wd + (size_t)(n0 + r1) * ID + c8;
  __bf16* lA0 = &As[(size_t)tid * 8];
  __bf16* lA1 = &As[(size_t)(tid + 256) * 8];
  __bf16* lB0 = &Bs[(size_t)tid * 8];
  __bf16* lB1 = &Bs[(size_t)(tid + 256) * 8];

  int wave = tid >> 6, lane = tid & 63;
  int wm = (wave >> 1) * 64, wn = (wave & 1) * 64;
  int l16 = lane & 15, kch = lane >> 4;

  f32x4 acc[4][4] = {};

  for (int k0 = 0; k0 < ID; k0 += BK) {
    gload16(gA0 + k0, lA0);
    gload16(gA1 + k0, lA1);
    gload16(gB0 + k0, lB0);
    gload16(gB1 + k0, lB1);
    __syncthreads();

    bf16x8 af[4], bf[4];
#pragma unroll
    for (int i = 0; i < 4; ++i) {
      af[i] = *(const bf16x8*)(&As[(wm + i * 16 + l16) * BK + kch * 8]);
      bf[i] = *(const bf16x8*)(&Bs[(wn + i * 16 + l16) * BK + kch * 8]);
    }
#pragma unroll
    for (int mi = 0; mi < 4; ++mi)
#pragma unroll
      for (int ni = 0; ni < 4; ++ni)
        acc[mi][ni] = mfma16(af[mi], bf[ni], acc[mi][ni]);
    __syncthreads();
  }

#pragma unroll
  for (int mi = 0; mi < 4; ++mi) {
#pragma unroll
    for (int j = 0; j < 4; ++j) {
      int row = m0 + wm + mi * 16 + kch * 4 + j;
      int token = slot_tok[row];
      if (token < 0) continue;
      float wgt = slot_w[row];
#pragma unroll
      for (int ni = 0; ni < 4; ++ni) {
        int col = n0 + wn + ni * 16 + l16;
        atomicAdd(out + (size_t)token * HD + col, wgt * acc[mi][ni][j]);
      }
    }
  }
}

// ============= fp32 fallback path (round-1 kernels, used if ws too small) ===

__global__ __launch_bounds__(256, 2) void pass1_gemm(
    const float* __restrict__ x, const int* __restrict__ slot_tok,
    const int* __restrict__ tile_e, const float* __restrict__ w1,
    const float* __restrict__ w3, const float* __restrict__ sw1,
    const float* __restrict__ sw3, __bf16* __restrict__ h1) {
  int mt = blockIdx.x;
  int e = tile_e[mt];
  if (e < 0) return;
  int n0 = blockIdx.y * BN;
  int m0 = mt * BM;

  const float* wg;
  const float* wu;
  if (e == NE) { wg = sw1; wu = sw3; }
  else { wg = w1 + (size_t)e * ID * HD; wu = w3 + (size_t)e * ID * HD; }

  __shared__ __bf16 As[BM][BK + 8];
  __shared__ __bf16 Bg[BN][BK + 8];
  __shared__ __bf16 Bu[BN][BK + 8];

  int tid = threadIdx.x;
  int lrow = tid >> 1;
  int lcol = (tid & 1) * 16;
  int tokenA = slot_tok[m0 + lrow];
  const float* aptr = x + (size_t)(tokenA < 0 ? 0 : tokenA) * HD + lcol;
  const float* gptr = wg + (size_t)(n0 + lrow) * HD + lcol;
  const float* uptr = wu + (size_t)(n0 + lrow) * HD + lcol;

  int wave = tid >> 6, lane = tid & 63;
  int wm = (wave >> 1) * 64, wn = (wave & 1) * 64;
  int l16 = lane & 15, kch = lane >> 4;

  f32x4 accg[4][4] = {};
  f32x4 accu[4][4] = {};

  for (int k0 = 0; k0 < HD; k0 += BK) {
    float4 av[4], gv[4], uv[4];
#pragma unroll
    for (int j = 0; j < 4; ++j) {
      av[j] = (tokenA >= 0) ? *(const float4*)(aptr + k0 + 4 * j)
                            : make_float4(0.f, 0.f, 0.f, 0.f);
      gv[j] = *(const float4*)(gptr + k0 + 4 * j);
      uv[j] = *(const float4*)(uptr + k0 + 4 * j);
    }
    __syncthreads();
#pragma unroll
    for (int j = 0; j < 4; ++j) {
      st_bf16x4(&As[lrow][lcol + 4 * j], av[j]);
      st_bf16x4(&Bg[lrow][lcol + 4 * j], gv[j]);
      st_bf16x4(&Bu[lrow][lcol + 4 * j], uv[j]);
    }
    __syncthreads();

    bf16x8 af[4], gf[4], uf[4];
#pragma unroll
    for (int i = 0; i < 4; ++i) {
      af[i] = *(const bf16x8*)(&As[wm + i * 16 + l16][kch * 8]);
      gf[i] = *(const bf16x8*)(&Bg[wn + i * 16 + l16][kch * 8]);
      uf[i] = *(const bf16x8*)(&Bu[wn + i * 16 + l16][kch * 8]);
    }
#pragma unroll
    for (int mi = 0; mi < 4; ++mi)
#pragma unroll
      for (int ni = 0; ni < 4; ++ni) {
        accg[mi][ni] = mfma16(af[mi], gf[ni], accg[mi][ni]);
        accu[mi][ni] = mfma16(af[mi], uf[ni], accu[mi][ni]);
      }
  }

#pragma unroll
  for (int mi = 0; mi < 4; ++mi) {
#pragma unroll
    for (int ni = 0; ni < 4; ++ni) {
#pragma unroll
      for (int j = 0; j < 4; ++j) {
        int row = m0 + wm + mi * 16 + kch * 4 + j;
        int col = n0 + wn + ni * 16 + l16;
        float g = accg[mi][ni][j];
        float u = accu[mi][ni][j];
        float hv = (g / (1.f + __expf(-g))) * u;
        h1[(size_t)row * ID + col] = (__bf16)hv;
      }
    }
  }
}

__global__ __launch_bounds__(256, 2) void pass2_gemm(
    const __bf16* __restrict__ h1, const int* __restrict__ slot_tok,
    const float* __restrict__ slot_w, const int* __restrict__ tile_e,
    const float* __restrict__ w2, const float* __restrict__ sw2,
    float* __restrict__ out) {
  int mt = blockIdx.x;
  int e = tile_e[mt];
  if (e < 0) return;
  int n0 = blockIdx.y * BN;
  int m0 = mt * BM;

  const float* wd = (e == NE) ? sw2 : (w2 + (size_t)e * HD * ID);

  __shared__ __bf16 As[BM][BK + 8];
  __shared__ __bf16 Bs[BN][BK + 8];

  int tid = threadIdx.x;
  int lrow = tid >> 1;
  int lcol = (tid & 1) * 16;
  const __bf16* aptr = h1 + (size_t)(m0 + lrow) * ID + lcol;
  const float* bptr = wd + (size_t)(n0 + lrow) * ID + lcol;

  int wave = tid >> 6, lane = tid & 63;
  int wm = (wave >> 1) * 64, wn = (wave & 1) * 64;
  int l16 = lane & 15, kch = lane >> 4;

  f32x4 acc[4][4] = {};

  for (int k0 = 0; k0 < ID; k0 += BK) {
    uint4 a0 = *(const uint4*)(aptr + k0);
    uint4 a1 = *(const uint4*)(aptr + k0 + 8);
    float4 bv[4];
#pragma unroll
    for (int j = 0; j < 4; ++j) bv[j] = *(const float4*)(bptr + k0 + 4 * j);
    __syncthreads();
    *(uint4*)(&As[lrow][lcol]) = a0;
    *(uint4*)(&As[lrow][lcol + 8]) = a1;
#pragma unroll
    for (int j = 0; j < 4; ++j) st_bf16x4(&Bs[lrow][lcol + 4 * j], bv[j]);
    __syncthreads();

    bf16x8 af[4], bf[4];
#pragma unroll
    for (int i = 0; i < 4; ++i) {
      af[i] = *(const bf16x8*)(&As[wm + i * 16 + l16][kch * 8]);
      bf[i] = *(const bf16x8*)(&Bs[wn + i * 16 + l16][kch * 8]);
    }
#pragma unroll
    for (int mi = 0; mi < 4; ++mi)
#pragma unroll
      for (int ni = 0; ni < 4; ++ni)
        acc[mi][ni] = mfma16(af[mi], bf[ni], acc[mi][ni]);
  }

#pragma unroll
  for (int mi = 0; mi < 4; ++mi) {
#pragma unroll
    for (int j = 0; j < 4; ++j) {
      int row = m0 + wm + mi * 16 + kch * 4 + j;
      int token = slot_tok[row];
      if (token < 0) continue;
      float wgt = slot_w[row];
#pragma unroll
      for (int ni = 0; ni < 4; ++ni) {
        int col = n0 + wn + ni * 16 + l16;
        atomicAdd(out + (size_t)token * HD + col, wgt * acc[mi][ni][j]);
      }
    }
  }
}

// ---------------- launcher ----------------
extern "C" void kernel_launch(void* const* d_in, const int* in_sizes, int n_in,
                              void* d_out, int out_size, void* d_ws, size_t ws_size,
                              hipStream_t stream) {
  const float* x = (const float*)d_in[0];
  const float* gate_w = (const float*)d_in[1];
  const float* ebias = (const float*)d_in[2];
  const float* w1 = (const float*)d_in[3];
  const float* w2 = (const float*)d_in[4];
  const float* w3 = (const float*)d_in[5];
  const float* sw1 = (const float*)d_in[6];
  const float* sw2 = (const float*)d_in[7];
  const float* sw3 = (const float*)d_in[8];
  float* out = (float*)d_out;

  char* ws = (char*)d_ws;
  int* cnt = (int*)(ws + WS_CNT);
  int* fillc = (int*)(ws + WS_FILL);
  int* off_g = (int*)(ws + WS_OFF);
  int* tile_e = (int*)(ws + WS_TILE_E);
  int* sel = (int*)(ws + WS_SEL);
  float* rw = (float*)(ws + WS_RW);
  int* slot_tok = (int*)(ws + WS_SLOT_TOK);
  float* slot_w = (float*)(ws + WS_SLOT_W);
  __bf16* h1 = (__bf16*)(ws + WS_H1);

  hipMemsetAsync(d_out, 0, (size_t)T_TOK * HD * sizeof(float), stream);
  hipMemsetAsync(ws, 0, 128, stream);  // cnt + fillc

  router_kernel<<<T_TOK, 64, 0, stream>>>(x, gate_w, ebias, sel, rw, cnt);
  scan_meta<<<1, 256, 0, stream>>>(cnt, off_g, tile_e, slot_tok, slot_w);
  fill_slots<<<(T_TOK * TOPK + 255) / 256, 256, 0, stream>>>(sel, rw, off_g, fillc,
                                                             slot_tok, slot_w);

  if (ws_size >= WS_NEED) {
    __bf16* xb = (__bf16*)(ws + WS_XB);
    __bf16* w1b = (__bf16*)(ws + WS_W1B);
    __bf16* w2b = (__bf16*)(ws + WS_W2B);
    __bf16* w3b = (__bf16*)(ws + WS_W3B);
    __bf16* sw1b = (__bf16*)(ws + WS_SW1B);
    __bf16* sw2b = (__bf16*)(ws + WS_SW2B);
    __bf16* sw3b = (__bf16*)(ws + WS_SW3B);

    const int nw8 = NE * ID * HD / 8;   // 2,097,152
    const int ns8 = ID * HD / 8;        // 131,072
    const int nx8 = T_TOK * HD / 8;     // 262,144
    cvt_bf16<<<(nw8 + 255) / 256, 256, 0, stream>>>(w1, w1b, nw8);
    cvt_bf16<<<(nw8 + 255) / 256, 256, 0, stream>>>(w2, w2b, nw8);
    cvt_bf16<<<(nw8 + 255) / 256, 256, 0, stream>>>(w3, w3b, nw8);
    cvt_bf16<<<(ns8 + 255) / 256, 256, 0, stream>>>(sw1, sw1b, ns8);
    cvt_bf16<<<(ns8 + 255) / 256, 256, 0, stream>>>(sw2, sw2b, ns8);
    cvt_bf16<<<(ns8 + 255) / 256, 256, 0, stream>>>(sw3, sw3b, ns8);
    cvt_bf16<<<(nx8 + 255) / 256, 256, 0, stream>>>(x, xb, nx8);

    pass1_bf16<<<dim3(ID / BN, MT_MAX), 256, 0, stream>>>(
        xb, slot_tok, tile_e, w1b, w3b, sw1b, sw3b, h1);
    pass2_bf16<<<dim3(HD / BN, MT_MAX), 256, 0, stream>>>(
        h1, slot_tok, slot_w, tile_e, w2b, sw2b, out);
  } else {
    pass1_gemm<<<dim3(MT_MAX, ID / BN), 256, 0, stream>>>(x, slot_tok, tile_e, w1,
                                                          w3, sw1, sw3, h1);
    pass2_gemm<<<dim3(MT_MAX, HD / BN), 256, 0, stream>>>(h1, slot_tok, slot_w,
                                                          tile_e, w2, sw2, out);
  }
}

// Round 3
// 261.524 us; speedup vs baseline: 1.6882x; 1.3249x over previous
//
#include <hip/hip_runtime.h>
#include <cstddef>
#include <cstdint>

#define T_TOK 2048
#define HD 1024
#define ID 1024
#define NE 16
#define TOPK 4
#define BM 128
#define BN 128
#define BK 32
#define MT_MAX 96
#define SLOT_CAP (MT_MAX * BM)

typedef float f32x4 __attribute__((ext_vector_type(4)));
typedef __bf16 bf16x8 __attribute__((ext_vector_type(8)));

// ---- workspace layout (bytes) ----
#define WS_CNT 0                          // int[16]
#define WS_FILL 64                        // int[16]
#define WS_OFF 128                        // int[17]
#define WS_TILE_E 256                     // int[MT_MAX]
#define WS_SEL 1024                       // int[8192]
#define WS_RW (WS_SEL + 8192 * 4)         // float[8192]
#define WS_LOGITS (WS_RW + 8192 * 4)      // float[2048*16]
#define WS_SLOT_TOK (WS_LOGITS + T_TOK * NE * 4)  // int[SLOT_CAP]
#define WS_SLOT_W (WS_SLOT_TOK + SLOT_CAP * 4)    // float[SLOT_CAP]
#define WS_H1 (WS_SLOT_W + SLOT_CAP * 4)          // __bf16[SLOT_CAP][ID]
#define WS_XB (WS_H1 + (size_t)SLOT_CAP * ID * 2)        // __bf16[T][H]
#define WS_W1B (WS_XB + (size_t)T_TOK * HD * 2)          // bf16 E*I*H
#define WS_W2B (WS_W1B + (size_t)NE * ID * HD * 2)
#define WS_W3B (WS_W2B + (size_t)NE * HD * ID * 2)
#define WS_SW1B (WS_W3B + (size_t)NE * ID * HD * 2)
#define WS_SW2B (WS_SW1B + (size_t)ID * HD * 2)
#define WS_SW3B (WS_SW2B + (size_t)HD * ID * 2)
#define WS_NEED (WS_SW3B + (size_t)ID * HD * 2)

__device__ __forceinline__ f32x4 mfma16(bf16x8 a, bf16x8 b, f32x4 c) {
  return __builtin_amdgcn_mfma_f32_16x16x32_bf16(a, b, c, 0, 0, 0);
}

__device__ __forceinline__ void st_bf16x4(__bf16* dst, float4 v) {
  __bf16 tmp[4] = {(__bf16)v.x, (__bf16)v.y, (__bf16)v.z, (__bf16)v.w};
  *(uint2*)dst = *(const uint2*)tmp;
}

// async global(16B/lane) -> LDS, linear dest (m97 pattern)
__device__ __forceinline__ void gload16(const __bf16* g, __bf16* l) {
  __builtin_amdgcn_global_load_lds(
      (const __attribute__((address_space(1))) uint32_t*)g,
      (__attribute__((address_space(3))) uint32_t*)l, 16, 0, 0);
}

// ---------------- fused fp32 -> bf16 convert of all tensors ----------------
#define NW8 (NE * (size_t)ID * HD / 8)  // 2,097,152 groups per big tensor
#define NS8 ((size_t)ID * HD / 8)       // 131,072
#define NX8 ((size_t)T_TOK * HD / 8)    // 262,144
#define CVT_TOTAL (3 * NW8 + 3 * NS8 + NX8)

__global__ __launch_bounds__(256) void cvt_all(
    const float* __restrict__ w1, const float* __restrict__ w2,
    const float* __restrict__ w3, const float* __restrict__ sw1,
    const float* __restrict__ sw2, const float* __restrict__ sw3,
    const float* __restrict__ x, __bf16* __restrict__ w1b,
    __bf16* __restrict__ w2b, __bf16* __restrict__ w3b,
    __bf16* __restrict__ sw1b, __bf16* __restrict__ sw2b,
    __bf16* __restrict__ sw3b, __bf16* __restrict__ xb) {
  size_t i = (size_t)blockIdx.x * 256 + threadIdx.x;
  if (i >= CVT_TOTAL) return;
  const float* src;
  __bf16* dst;
  size_t off;
  if (i < NW8) { src = w1; dst = w1b; off = i; }
  else if (i < 2 * NW8) { src = w2; dst = w2b; off = i - NW8; }
  else if (i < 3 * NW8) { src = w3; dst = w3b; off = i - 2 * NW8; }
  else if (i < 3 * NW8 + NS8) { src = sw1; dst = sw1b; off = i - 3 * NW8; }
  else if (i < 3 * NW8 + 2 * NS8) { src = sw2; dst = sw2b; off = i - 3 * NW8 - NS8; }
  else if (i < 3 * NW8 + 3 * NS8) { src = sw3; dst = sw3b; off = i - 3 * NW8 - 2 * NS8; }
  else { src = x; dst = xb; off = i - 3 * NW8 - 3 * NS8; }

  const float4* p = (const float4*)src + 2 * off;
  float4 a = p[0], b = p[1];
  bf16x8 o;
  o[0] = (__bf16)a.x; o[1] = (__bf16)a.y; o[2] = (__bf16)a.z; o[3] = (__bf16)a.w;
  o[4] = (__bf16)b.x; o[5] = (__bf16)b.y; o[6] = (__bf16)b.z; o[7] = (__bf16)b.w;
  *(bf16x8*)(dst + 8 * off) = o;
}

// ---------------- router stage 1: logits = x @ gate_w^T ----------------
// 4 waves/block, 1 token/wave, lane = expert*4 + quarter(H/4 chunk)
__global__ __launch_bounds__(256) void router_logits(
    const float* __restrict__ x, const float* __restrict__ gw,
    float* __restrict__ logits) {
  int tid = threadIdx.x;
  int wv = tid >> 6;
  int lane = tid & 63;
  int tok = blockIdx.x * 4 + wv;
  int e = lane >> 2;
  int q = lane & 3;
  const float4* xr = (const float4*)(x + (size_t)tok * HD) + q * 64;
  const float4* wr = (const float4*)(gw + (size_t)e * HD) + q * 64;
  float s0 = 0.f, s1 = 0.f;
#pragma unroll 8
  for (int i = 0; i < 64; i += 2) {
    float4 a0 = xr[i], w0 = wr[i];
    float4 a1 = xr[i + 1], w1 = wr[i + 1];
    s0 += a0.x * w0.x + a0.y * w0.y + a0.z * w0.z + a0.w * w0.w;
    s1 += a1.x * w1.x + a1.y * w1.y + a1.z * w1.z + a1.w * w1.w;
  }
  float s = s0 + s1;
  s += __shfl_xor(s, 1);
  s += __shfl_xor(s, 2);
  if (q == 0) logits[(size_t)tok * NE + e] = s;
}

// ---------------- router stage 2: top-4 + softmax + counts ----------------
__global__ __launch_bounds__(256) void router_topk(
    const float* __restrict__ logits, const float* __restrict__ bias,
    int* __restrict__ sel, float* __restrict__ rw, int* __restrict__ cnt) {
  __shared__ int hist[NE];
  int tid = threadIdx.x;
  if (tid < NE) hist[tid] = 0;
  __syncthreads();
  int t = blockIdx.x * 256 + tid;

  float lg[NE];
  const float4* lp = (const float4*)(logits + (size_t)t * NE);
#pragma unroll
  for (int j = 0; j < 4; ++j) {
    float4 v = lp[j];
    lg[4 * j] = v.x; lg[4 * j + 1] = v.y; lg[4 * j + 2] = v.z; lg[4 * j + 3] = v.w;
  }
  float b[NE];
#pragma unroll
  for (int e = 0; e < NE; ++e) b[e] = lg[e] + bias[e];

  int selk[TOPK];
  float raw[TOPK];
  unsigned used = 0;
#pragma unroll
  for (int k = 0; k < TOPK; ++k) {
    float best = -3.4e38f;
    int bi = 0;
#pragma unroll
    for (int e = 0; e < NE; ++e) {
      if (!((used >> e) & 1) && b[e] > best) { best = b[e]; bi = e; }
    }
    used |= (1u << bi);
    selk[k] = bi;
    raw[k] = lg[bi];
  }
  float m = raw[0];
#pragma unroll
  for (int k = 1; k < TOPK; ++k) m = fmaxf(m, raw[k]);
  float s = 0.f;
  float w[TOPK];
#pragma unroll
  for (int k = 0; k < TOPK; ++k) { w[k] = __expf(raw[k] - m); s += w[k]; }
  float inv = 1.f / s;
#pragma unroll
  for (int k = 0; k < TOPK; ++k) {
    sel[t * TOPK + k] = selk[k];
    rw[t * TOPK + k] = w[k] * inv;
    atomicAdd(&hist[selk[k]], 1);
  }
  __syncthreads();
  if (tid < NE) atomicAdd(&cnt[tid], hist[tid]);
}

// ---------------- scan: aligned offsets + metadata ----------------
__global__ void scan_meta(const int* __restrict__ cnt, int* __restrict__ off_g,
                          int* __restrict__ tile_e, int* __restrict__ slot_tok,
                          float* __restrict__ slot_w) {
  __shared__ int s_off[NE + 1];
  int tid = threadIdx.x;
  if (tid == 0) {
    int o = 0;
    for (int e = 0; e < NE; ++e) {
      s_off[e] = o;
      o += (cnt[e] + BM - 1) & ~(BM - 1);
    }
    s_off[NE] = o;
    for (int i = 0; i <= NE; ++i) off_g[i] = s_off[i];
  }
  __syncthreads();
  int shared_base = s_off[NE];
  int total = shared_base + T_TOK;

  for (int tt = tid; tt < MT_MAX; tt += 256) {
    int base = tt * BM;
    int e = -1;
    if (base < shared_base) {
      for (int q = NE - 1; q >= 0; --q)
        if (base >= s_off[q]) { e = q; break; }
    } else if (base < total) {
      e = NE;  // shared expert
    }
    tile_e[tt] = e;
  }

  for (int s = tid; s < total; s += 256) {
    if (s >= shared_base) {
      slot_tok[s] = s - shared_base;
      slot_w[s] = 1.0f;
    } else {
      int e = 0;
      for (int q = NE - 1; q >= 0; --q)
        if (s >= s_off[q]) { e = q; break; }
      if (s >= s_off[e] + cnt[e]) {  // padding slot
        slot_tok[s] = -1;
        slot_w[s] = 0.f;
      }
    }
  }
}

// ---------------- fill routed slots ----------------
__global__ void fill_slots(const int* __restrict__ sel, const float* __restrict__ rw,
                           const int* __restrict__ off_g, int* __restrict__ fillc,
                           int* __restrict__ slot_tok, float* __restrict__ slot_w) {
  int idx = blockIdx.x * 256 + threadIdx.x;
  if (idx >= T_TOK * TOPK) return;
  int t = idx >> 2;
  int e = sel[idx];
  int pos = atomicAdd(&fillc[e], 1);
  int s = off_g[e] + pos;
  slot_tok[s] = t;
  slot_w[s] = rw[idx];
}

// ============= bf16 fast path (m97 structure: global_load_lds, BK=32) =======

// pass 1: h1 = silu(x w1^T) * (x w3^T)
__global__ __launch_bounds__(256, 2) void pass1_bf16(
    const __bf16* __restrict__ xb, const int* __restrict__ slot_tok,
    const int* __restrict__ tile_e, const __bf16* __restrict__ w1b,
    const __bf16* __restrict__ w3b, const __bf16* __restrict__ sw1b,
    const __bf16* __restrict__ sw3b, __bf16* __restrict__ h1) {
  int mt = blockIdx.y;
  int e = tile_e[mt];
  if (e < 0) return;
  int n0 = blockIdx.x * BN;
  int m0 = mt * BM;

  const __bf16* wg = (e == NE) ? sw1b : w1b + (size_t)e * ID * HD;
  const __bf16* wu = (e == NE) ? sw3b : w3b + (size_t)e * ID * HD;

  __shared__ __align__(16) __bf16 As[BM * BK];
  __shared__ __align__(16) __bf16 Bg[BN * BK];
  __shared__ __align__(16) __bf16 Bu[BN * BK];

  int tid = threadIdx.x;
  int r0 = tid >> 2, r1 = r0 + 64;
  int c8 = (tid & 3) * 8;
  int tok0 = slot_tok[m0 + r0]; if (tok0 < 0) tok0 = 0;
  int tok1 = slot_tok[m0 + r1]; if (tok1 < 0) tok1 = 0;
  const __bf16* gA0 = xb + (size_t)tok0 * HD + c8;
  const __bf16* gA1 = xb + (size_t)tok1 * HD + c8;
  const __bf16* gG0 = wg + (size_t)(n0 + r0) * HD + c8;
  const __bf16* gG1 = wg + (size_t)(n0 + r1) * HD + c8;
  const __bf16* gU0 = wu + (size_t)(n0 + r0) * HD + c8;
  const __bf16* gU1 = wu + (size_t)(n0 + r1) * HD + c8;
  __bf16* lA0 = &As[(size_t)tid * 8];
  __bf16* lA1 = &As[(size_t)(tid + 256) * 8];
  __bf16* lG0 = &Bg[(size_t)tid * 8];
  __bf16* lG1 = &Bg[(size_t)(tid + 256) * 8];
  __bf16* lU0 = &Bu[(size_t)tid * 8];
  __bf16* lU1 = &Bu[(size_t)(tid + 256) * 8];

  int wave = tid >> 6, lane = tid & 63;
  int wm = (wave >> 1) * 64, wn = (wave & 1) * 64;
  int l16 = lane & 15, kch = lane >> 4;

  f32x4 accg[4][4] = {};
  f32x4 accu[4][4] = {};

  for (int k0 = 0; k0 < HD; k0 += BK) {
    gload16(gA0 + k0, lA0);
    gload16(gA1 + k0, lA1);
    gload16(gG0 + k0, lG0);
    gload16(gG1 + k0, lG1);
    gload16(gU0 + k0, lU0);
    gload16(gU1 + k0, lU1);
    __syncthreads();

    bf16x8 af[4], gf[4], uf[4];
#pragma unroll
    for (int i = 0; i < 4; ++i) {
      af[i] = *(const bf16x8*)(&As[(wm + i * 16 + l16) * BK + kch * 8]);
      gf[i] = *(const bf16x8*)(&Bg[(wn + i * 16 + l16) * BK + kch * 8]);
      uf[i] = *(const bf16x8*)(&Bu[(wn + i * 16 + l16) * BK + kch * 8]);
    }
#pragma unroll
    for (int mi = 0; mi < 4; ++mi)
#pragma unroll
      for (int ni = 0; ni < 4; ++ni) {
        accg[mi][ni] = mfma16(af[mi], gf[ni], accg[mi][ni]);
        accu[mi][ni] = mfma16(af[mi], uf[ni], accu[mi][ni]);
      }
    __syncthreads();
  }

#pragma unroll
  for (int mi = 0; mi < 4; ++mi) {
#pragma unroll
    for (int ni = 0; ni < 4; ++ni) {
#pragma unroll
      for (int j = 0; j < 4; ++j) {
        int row = m0 + wm + mi * 16 + kch * 4 + j;
        int col = n0 + wn + ni * 16 + l16;
        float g = accg[mi][ni][j];
        float u = accu[mi][ni][j];
        float hv = (g / (1.f + __expf(-g))) * u;
        h1[(size_t)row * ID + col] = (__bf16)hv;
      }
    }
  }
}

// pass 2: out += g * (h1 w2^T)
__global__ __launch_bounds__(256, 2) void pass2_bf16(
    const __bf16* __restrict__ h1, const int* __restrict__ slot_tok,
    const float* __restrict__ slot_w, const int* __restrict__ tile_e,
    const __bf16* __restrict__ w2b, const __bf16* __restrict__ sw2b,
    float* __restrict__ out) {
  int mt = blockIdx.y;
  int e = tile_e[mt];
  if (e < 0) return;
  int n0 = blockIdx.x * BN;
  int m0 = mt * BM;

  const __bf16* wd = (e == NE) ? sw2b : w2b + (size_t)e * HD * ID;

  __shared__ __align__(16) __bf16 As[BM * BK];
  __shared__ __align__(16) __bf16 Bs[BN * BK];

  int tid = threadIdx.x;
  int r0 = tid >> 2, r1 = r0 + 64;
  int c8 = (tid & 3) * 8;
  const __bf16* gA0 = h1 + (size_t)(m0 + r0) * ID + c8;
  const __bf16* gA1 = h1 + (size_t)(m0 + r1) * ID + c8;
  const __bf16* gB0 = wd + (size_t)(n0 + r0) * ID + c8;
  const __bf16* gB1 = wd + (size_t)(n0 + r1) * ID + c8;
  __bf16* lA0 = &As[(size_t)tid * 8];
  __bf16* lA1 = &As[(size_t)(tid + 256) * 8];
  __bf16* lB0 = &Bs[(size_t)tid * 8];
  __bf16* lB1 = &Bs[(size_t)(tid + 256) * 8];

  int wave = tid >> 6, lane = tid & 63;
  int wm = (wave >> 1) * 64, wn = (wave & 1) * 64;
  int l16 = lane & 15, kch = lane >> 4;

  f32x4 acc[4][4] = {};

  for (int k0 = 0; k0 < ID; k0 += BK) {
    gload16(gA0 + k0, lA0);
    gload16(gA1 + k0, lA1);
    gload16(gB0 + k0, lB0);
    gload16(gB1 + k0, lB1);
    __syncthreads();

    bf16x8 af[4], bf[4];
#pragma unroll
    for (int i = 0; i < 4; ++i) {
      af[i] = *(const bf16x8*)(&As[(wm + i * 16 + l16) * BK + kch * 8]);
      bf[i] = *(const bf16x8*)(&Bs[(wn + i * 16 + l16) * BK + kch * 8]);
    }
#pragma unroll
    for (int mi = 0; mi < 4; ++mi)
#pragma unroll
      for (int ni = 0; ni < 4; ++ni)
        acc[mi][ni] = mfma16(af[mi], bf[ni], acc[mi][ni]);
    __syncthreads();
  }

#pragma unroll
  for (int mi = 0; mi < 4; ++mi) {
#pragma unroll
    for (int j = 0; j < 4; ++j) {
      int row = m0 + wm + mi * 16 + kch * 4 + j;
      int token = slot_tok[row];
      if (token < 0) continue;
      float wgt = slot_w[row];
#pragma unroll
      for (int ni = 0; ni < 4; ++ni) {
        int col = n0 + wn + ni * 16 + l16;
        atomicAdd(out + (size_t)token * HD + col, wgt * acc[mi][ni][j]);
      }
    }
  }
}

// ============= fp32 fallback path (used only if ws too small) ===============

__global__ __launch_bounds__(256, 2) void pass1_gemm(
    const float* __restrict__ x, const int* __restrict__ slot_tok,
    const int* __restrict__ tile_e, const float* __restrict__ w1,
    const float* __restrict__ w3, const float* __restrict__ sw1,
    const float* __restrict__ sw3, __bf16* __restrict__ h1) {
  int mt = blockIdx.x;
  int e = tile_e[mt];
  if (e < 0) return;
  int n0 = blockIdx.y * BN;
  int m0 = mt * BM;

  const float* wg;
  const float* wu;
  if (e == NE) { wg = sw1; wu = sw3; }
  else { wg = w1 + (size_t)e * ID * HD; wu = w3 + (size_t)e * ID * HD; }

  __shared__ __bf16 As[BM][BK + 8];
  __shared__ __bf16 Bg[BN][BK + 8];
  __shared__ __bf16 Bu[BN][BK + 8];

  int tid = threadIdx.x;
  int lrow = tid >> 1;
  int lcol = (tid & 1) * 16;
  int tokenA = slot_tok[m0 + lrow];
  const float* aptr = x + (size_t)(tokenA < 0 ? 0 : tokenA) * HD + lcol;
  const float* gptr = wg + (size_t)(n0 + lrow) * HD + lcol;
  const float* uptr = wu + (size_t)(n0 + lrow) * HD + lcol;

  int wave = tid >> 6, lane = tid & 63;
  int wm = (wave >> 1) * 64, wn = (wave & 1) * 64;
  int l16 = lane & 15, kch = lane >> 4;

  f32x4 accg[4][4] = {};
  f32x4 accu[4][4] = {};

  for (int k0 = 0; k0 < HD; k0 += BK) {
    float4 av[4], gv[4], uv[4];
#pragma unroll
    for (int j = 0; j < 4; ++j) {
      av[j] = (tokenA >= 0) ? *(const float4*)(aptr + k0 + 4 * j)
                            : make_float4(0.f, 0.f, 0.f, 0.f);
      gv[j] = *(const float4*)(gptr + k0 + 4 * j);
      uv[j] = *(const float4*)(uptr + k0 + 4 * j);
    }
    __syncthreads();
#pragma unroll
    for (int j = 0; j < 4; ++j) {
      st_bf16x4(&As[lrow][lcol + 4 * j], av[j]);
      st_bf16x4(&Bg[lrow][lcol + 4 * j], gv[j]);
      st_bf16x4(&Bu[lrow][lcol + 4 * j], uv[j]);
    }
    __syncthreads();

    bf16x8 af[4], gf[4], uf[4];
#pragma unroll
    for (int i = 0; i < 4; ++i) {
      af[i] = *(const bf16x8*)(&As[wm + i * 16 + l16][kch * 8]);
      gf[i] = *(const bf16x8*)(&Bg[wn + i * 16 + l16][kch * 8]);
      uf[i] = *(const bf16x8*)(&Bu[wn + i * 16 + l16][kch * 8]);
    }
#pragma unroll
    for (int mi = 0; mi < 4; ++mi)
#pragma unroll
      for (int ni = 0; ni < 4; ++ni) {
        accg[mi][ni] = mfma16(af[mi], gf[ni], accg[mi][ni]);
        accu[mi][ni] = mfma16(af[mi], uf[ni], accu[mi][ni]);
      }
  }

#pragma unroll
  for (int mi = 0; mi < 4; ++mi) {
#pragma unroll
    for (int ni = 0; ni < 4; ++ni) {
#pragma unroll
      for (int j = 0; j < 4; ++j) {
        int row = m0 + wm + mi * 16 + kch * 4 + j;
        int col = n0 + wn + ni * 16 + l16;
        float g = accg[mi][ni][j];
        float u = accu[mi][ni][j];
        float hv = (g / (1.f + __expf(-g))) * u;
        h1[(size_t)row * ID + col] = (__bf16)hv;
      }
    }
  }
}

__global__ __launch_bounds__(256, 2) void pass2_gemm(
    const __bf16* __restrict__ h1, const int* __restrict__ slot_tok,
    const float* __restrict__ slot_w, const int* __restrict__ tile_e,
    const float* __restrict__ w2, const float* __restrict__ sw2,
    float* __restrict__ out) {
  int mt = blockIdx.x;
  int e = tile_e[mt];
  if (e < 0) return;
  int n0 = blockIdx.y * BN;
  int m0 = mt * BM;

  const float* wd = (e == NE) ? sw2 : (w2 + (size_t)e * HD * ID);

  __shared__ __bf16 As[BM][BK + 8];
  __shared__ __bf16 Bs[BN][BK + 8];

  int tid = threadIdx.x;
  int lrow = tid >> 1;
  int lcol = (tid & 1) * 16;
  const __bf16* aptr = h1 + (size_t)(m0 + lrow) * ID + lcol;
  const float* bptr = wd + (size_t)(n0 + lrow) * ID + lcol;

  int wave = tid >> 6, lane = tid & 63;
  int wm = (wave >> 1) * 64, wn = (wave & 1) * 64;
  int l16 = lane & 15, kch = lane >> 4;

  f32x4 acc[4][4] = {};

  for (int k0 = 0; k0 < ID; k0 += BK) {
    uint4 a0 = *(const uint4*)(aptr + k0);
    uint4 a1 = *(const uint4*)(aptr + k0 + 8);
    float4 bv[4];
#pragma unroll
    for (int j = 0; j < 4; ++j) bv[j] = *(const float4*)(bptr + k0 + 4 * j);
    __syncthreads();
    *(uint4*)(&As[lrow][lcol]) = a0;
    *(uint4*)(&As[lrow][lcol + 8]) = a1;
#pragma unroll
    for (int j = 0; j < 4; ++j) st_bf16x4(&Bs[lrow][lcol + 4 * j], bv[j]);
    __syncthreads();

    bf16x8 af[4], bf[4];
#pragma unroll
    for (int i = 0; i < 4; ++i) {
      af[i] = *(const bf16x8*)(&As[wm + i * 16 + l16][kch * 8]);
      bf[i] = *(const bf16x8*)(&Bs[wn + i * 16 + l16][kch * 8]);
    }
#pragma unroll
    for (int mi = 0; mi < 4; ++mi)
#pragma unroll
      for (int ni = 0; ni < 4; ++ni)
        acc[mi][ni] = mfma16(af[mi], bf[ni], acc[mi][ni]);
  }

#pragma unroll
  for (int mi = 0; mi < 4; ++mi) {
#pragma unroll
    for (int j = 0; j < 4; ++j) {
      int row = m0 + wm + mi * 16 + kch * 4 + j;
      int token = slot_tok[row];
      if (token < 0) continue;
      float wgt = slot_w[row];
#pragma unroll
      for (int ni = 0; ni < 4; ++ni) {
        int col = n0 + wn + ni * 16 + l16;
        atomicAdd(out + (size_t)token * HD + col, wgt * acc[mi][ni][j]);
      }
    }
  }
}

// ---------------- launcher ----------------
extern "C" void kernel_launch(void* const* d_in, const int* in_sizes, int n_in,
                              void* d_out, int out_size, void* d_ws, size_t ws_size,
                              hipStream_t stream) {
  const float* x = (const float*)d_in[0];
  const float* gate_w = (const float*)d_in[1];
  const float* ebias = (const float*)d_in[2];
  const float* w1 = (const float*)d_in[3];
  const float* w2 = (const float*)d_in[4];
  const float* w3 = (const float*)d_in[5];
  const float* sw1 = (const float*)d_in[6];
  const float* sw2 = (const float*)d_in[7];
  const float* sw3 = (const float*)d_in[8];
  float* out = (float*)d_out;

  char* ws = (char*)d_ws;
  int* cnt = (int*)(ws + WS_CNT);
  int* fillc = (int*)(ws + WS_FILL);
  int* off_g = (int*)(ws + WS_OFF);
  int* tile_e = (int*)(ws + WS_TILE_E);
  int* sel = (int*)(ws + WS_SEL);
  float* rw = (float*)(ws + WS_RW);
  float* logits = (float*)(ws + WS_LOGITS);
  int* slot_tok = (int*)(ws + WS_SLOT_TOK);
  float* slot_w = (float*)(ws + WS_SLOT_W);
  __bf16* h1 = (__bf16*)(ws + WS_H1);

  hipMemsetAsync(d_out, 0, (size_t)T_TOK * HD * sizeof(float), stream);
  hipMemsetAsync(ws, 0, 128, stream);  // cnt + fillc

  router_logits<<<T_TOK / 4, 256, 0, stream>>>(x, gate_w, logits);
  router_topk<<<T_TOK / 256, 256, 0, stream>>>(logits, ebias, sel, rw, cnt);
  scan_meta<<<1, 256, 0, stream>>>(cnt, off_g, tile_e, slot_tok, slot_w);
  fill_slots<<<(T_TOK * TOPK + 255) / 256, 256, 0, stream>>>(sel, rw, off_g, fillc,
                                                             slot_tok, slot_w);

  if (ws_size >= WS_NEED) {
    __bf16* xb = (__bf16*)(ws + WS_XB);
    __bf16* w1b = (__bf16*)(ws + WS_W1B);
    __bf16* w2b = (__bf16*)(ws + WS_W2B);
    __bf16* w3b = (__bf16*)(ws + WS_W3B);
    __bf16* sw1b = (__bf16*)(ws + WS_SW1B);
    __bf16* sw2b = (__bf16*)(ws + WS_SW2B);
    __bf16* sw3b = (__bf16*)(ws + WS_SW3B);

    cvt_all<<<(int)((CVT_TOTAL + 255) / 256), 256, 0, stream>>>(
        w1, w2, w3, sw1, sw2, sw3, x, w1b, w2b, w3b, sw1b, sw2b, sw3b, xb);

    pass1_bf16<<<dim3(ID / BN, MT_MAX), 256, 0, stream>>>(
        xb, slot_tok, tile_e, w1b, w3b, sw1b, sw3b, h1);
    pass2_bf16<<<dim3(HD / BN, MT_MAX), 256, 0, stream>>>(
        h1, slot_tok, slot_w, tile_e, w2b, sw2b, out);
  } else {
    pass1_gemm<<<dim3(MT_MAX, ID / BN), 256, 0, stream>>>(x, slot_tok, tile_e, w1,
                                                          w3, sw1, sw3, h1);
    pass2_gemm<<<dim3(MT_MAX, HD / BN), 256, 0, stream>>>(h1, slot_tok, slot_w,
                                                          tile_e, w2, sw2, out);
  }
}